// Round 6
// baseline (48.547 us; speedup 1.0000x reference)
//
#include <hip/hip_runtime.h>

// DilateAttention: q,k,v [B=16, d=32, H=128, W=128] fp32, kernel=3, dilation=2, pad=2.
// Per-pixel 1x9 attention over dilated 3x3 window; OOB taps are zero-padded
// (score 0, value 0) and participate in the softmax denominator.
//
// R6: cut VMEM instruction count 4x (the measured bottleneck: issue+latency,
// data is L3-resident). 2 pixels/thread via float2 + 2-way d-split keeps
// 4096 waves (16/CU). Kept from R4: clamped UNpredicated loads + tv[]
// cancellation, 4-d phase-split load batches (~40 loads in flight), XCD-chunk
// swizzle. d-half score reduction = one shfl_xor(32) per tap, no LDS.

#define BB 16
#define HD 32
#define HH 128
#define WW 128
#define PLANE (HH * WW)
#define CHUNK 4
#define HALF 16   // d's per d-half

__global__ __launch_bounds__(256, 4) void dilate_attn_kernel(
    const float* __restrict__ q,
    const float* __restrict__ k,
    const float* __restrict__ v,
    float* __restrict__ out)
{
    const int tid   = threadIdx.x;
    const int lane  = tid & 63;
    const int dh    = lane >> 5;           // 0/1: d in [dh*16, dh*16+16)
    const int wsub  = lane & 31;           // 0..31
    const int wave  = tid >> 6;            // 0..3
    const int lr    = wave >> 1;           // 0/1 local row
    const int whalf = wave & 1;            // 0/1 w-half
    const int w2    = whalf * 64 + wsub * 2;   // even pixel: covers w2, w2+1

    const int bid   = blockIdx.x;                    // 0..1023
    const int tile  = (bid & 7) * 128 + (bid >> 3);  // XCD-chunk swizzle
    const int rowid = tile * 2 + lr;                 // 0..2047
    const int h = rowid & (HH - 1);
    const int b = rowid >> 7;

    const size_t dbase = ((size_t)b * HD + (size_t)dh * HALF) * PLANE;
    const int pix = h * WW + w2;

    // Clamped (always in-bounds) tap offsets; garbage cancelled via tv0/tv1.
    const int dlo = (w2 >= 2)   ? -2      : 0;
    const int dhi = (w2 <= 124) ?  2      : 0;
    const int roff[3] = { (h >= 2) ? -2 * WW : 0, 0, (h <= HH - 3) ? 2 * WW : 0 };
    const bool hlo = (h >= 2), hhi = (h <= HH - 3);
    const bool wlo0 = (w2 >= 2), wlo1 = (w2 >= 1);
    const bool whi0 = (w2 <= 125), whi1 = (w2 <= 124);
    const bool tv0[9] = { hlo && wlo0, hlo, hlo && whi0,
                          wlo0,        true, whi0,
                          hhi && wlo0, hhi, hhi && whi0 };
    const bool tv1[9] = { hlo && wlo1, hlo, hlo && whi1,
                          wlo1,        true, whi1,
                          hhi && wlo1, hhi, hhi && whi1 };

    // ---- Pass 1: partial scores over this d-half (phase-split batches) ----
    float s0[9], s1[9];
    #pragma unroll
    for (int n = 0; n < 9; ++n) { s0[n] = 0.f; s1[n] = 0.f; }

    const float* qp = q + dbase + pix;
    const float* kp = k + dbase + pix;

    #pragma unroll 1
    for (int c = 0; c < HALF; c += CHUNK) {
        float2 qreg[CHUNK], kreg[CHUNK][9];
        #pragma unroll
        for (int u = 0; u < CHUNK; ++u) {
            const float* kc = kp + (size_t)(c + u) * PLANE;
            qreg[u] = *(const float2*)(qp + (size_t)(c + u) * PLANE);
            #pragma unroll
            for (int ti = 0; ti < 3; ++ti) {
                const float* kr = kc + roff[ti];
                kreg[u][ti * 3 + 0] = *(const float2*)(kr + dlo);
                kreg[u][ti * 3 + 1] = *(const float2*)(kr);
                kreg[u][ti * 3 + 2] = *(const float2*)(kr + dhi);
            }
        }
        #pragma unroll
        for (int u = 0; u < CHUNK; ++u) {
            #pragma unroll
            for (int n = 0; n < 9; ++n) {
                s0[n] = fmaf(qreg[u].x, kreg[u][n].x, s0[n]);
                s1[n] = fmaf(qreg[u].y, kreg[u][n].y, s1[n]);
            }
        }
    }

    // ---- Reduce the two d-halves: lanes differing in bit 5 ----
    #pragma unroll
    for (int n = 0; n < 9; ++n) {
        s0[n] += __shfl_xor(s0[n], 32);
        s1[n] += __shfl_xor(s1[n], 32);
    }

    // Cancel garbage (invalid taps: score exactly 0, still in denominator).
    #pragma unroll
    for (int n = 0; n < 9; ++n) { if (!tv0[n]) s0[n] = 0.f; if (!tv1[n]) s1[n] = 0.f; }

    // ---- Softmax over 9 taps, per pixel ----
    const float scale = 0.17677669529663687f;  // 32^-0.5
    {
        float m0 = -3.4e38f, m1 = -3.4e38f;
        #pragma unroll
        for (int n = 0; n < 9; ++n) {
            s0[n] *= scale; m0 = fmaxf(m0, s0[n]);
            s1[n] *= scale; m1 = fmaxf(m1, s1[n]);
        }
        float sum0 = 0.f, sum1 = 0.f;
        #pragma unroll
        for (int n = 0; n < 9; ++n) {
            s0[n] = __expf(s0[n] - m0); sum0 += s0[n];
            s1[n] = __expf(s1[n] - m1); sum1 += s1[n];
        }
        const float i0 = 1.f / sum0, i1 = 1.f / sum1;
        #pragma unroll
        for (int n = 0; n < 9; ++n) { s0[n] *= i0; s1[n] *= i1; }
    }

    // Zero weights of invalid taps (reference v is zero-padded there).
    #pragma unroll
    for (int n = 0; n < 9; ++n) { if (!tv0[n]) s0[n] = 0.f; if (!tv1[n]) s1[n] = 0.f; }

    // ---- Pass 2: PV for this d-half (phase-split batches) ----
    const float* vp = v + dbase + pix;
    float*       op = out + dbase + pix;

    #pragma unroll 1
    for (int c = 0; c < HALF; c += CHUNK) {
        float2 vreg[CHUNK][9];
        #pragma unroll
        for (int u = 0; u < CHUNK; ++u) {
            const float* vc = vp + (size_t)(c + u) * PLANE;
            #pragma unroll
            for (int ti = 0; ti < 3; ++ti) {
                const float* vr = vc + roff[ti];
                vreg[u][ti * 3 + 0] = *(const float2*)(vr + dlo);
                vreg[u][ti * 3 + 1] = *(const float2*)(vr);
                vreg[u][ti * 3 + 2] = *(const float2*)(vr + dhi);
            }
        }
        #pragma unroll
        for (int u = 0; u < CHUNK; ++u) {
            float a0 = 0.f, a1 = 0.f;
            #pragma unroll
            for (int n = 0; n < 9; ++n) {
                a0 = fmaf(s0[n], vreg[u][n].x, a0);
                a1 = fmaf(s1[n], vreg[u][n].y, a1);
            }
            *(float2*)(op + (size_t)(c + u) * PLANE) = make_float2(a0, a1);
        }
    }
}

extern "C" void kernel_launch(void* const* d_in, const int* in_sizes, int n_in,
                              void* d_out, int out_size, void* d_ws, size_t ws_size,
                              hipStream_t stream) {
    const float* q = (const float*)d_in[0];
    const float* k = (const float*)d_in[1];
    const float* v = (const float*)d_in[2];
    float* out = (float*)d_out;

    dim3 grid(BB * HH / 2);  // 1024 blocks, 2 (b,h) rows each
    dim3 block(256);         // 4 waves: 2 rows x 2 w-halves x 2 d-halves
    dilate_attn_kernel<<<grid, block, 0, stream>>>(q, k, v, out);
}

// Round 7
// 40.048 us; speedup vs baseline: 1.2122x; 1.2122x over previous
//
#include <hip/hip_runtime.h>

// DilateAttention: q,k,v [B=16, d=32, H=128, W=128] fp32, kernel=3, dilation=2, pad=2.
// Per-pixel 1x9 attention over dilated 3x3 window; OOB taps are zero-padded
// (score 0, value 0) and participate in the softmax denominator.
//
// R7: reduce wave-level VMEM issues 4x (R6 post-mortem: float2+pixel-halving
// kept issues/pixel constant at 10; this gets 2.5). 4 pixels/thread via
// aligned float4: per (d, tap-row), 3 float4 loads (cols w4-4..w4+7) serve
// all 3 j-taps of 4 pixels. 2-way d-split across lane bit 5 keeps 2048 waves
// (8/CU); score reduction = one shfl_xor(32) per tap. Wave = one full output
// row, so row validity is wave-uniform. Kept: clamped UNpredicated loads +
// tv[] cancellation, CHUNK=2 phase-split, XCD-chunk swizzle.

#define BB 16
#define HD 32
#define HH 128
#define WW 128
#define PLANE (HH * WW)
#define CHUNK 2
#define HALF 16   // d's per d-half

__global__ __launch_bounds__(256, 2) void dilate_attn_kernel(
    const float* __restrict__ q,
    const float* __restrict__ k,
    const float* __restrict__ v,
    float* __restrict__ out)
{
    const int tid  = threadIdx.x;
    const int lane = tid & 63;
    const int wv   = tid >> 6;         // wave 0..3 = row within block
    const int dh   = lane >> 5;        // d-half 0/1
    const int lw   = lane & 31;        // 0..31
    const int w4   = lw * 4;           // pixels w4..w4+3

    const int bid   = blockIdx.x;                   // 0..511
    const int tile  = (bid & 7) * 64 + (bid >> 3);  // XCD-chunk swizzle
    const int rowid = tile * 4 + wv;                // 0..2047
    const int h = rowid & (HH - 1);
    const int b = rowid >> 7;

    const size_t dbase = ((size_t)b * HD + (size_t)dh * HALF) * PLANE;
    const int rowbase = h * WW;

    // Wave-uniform row validity; clamped row offsets.
    const bool hlo = (h >= 2), hhi = (h <= HH - 3);
    const int roff[3] = { hlo ? -2 * WW : 0, 0, hhi ? 2 * WW : 0 };

    // Aligned, clamped column-chunk bases. Garbage feeds only cancelled taps.
    const int lo_c = (w4 >= 4)      ? w4 - 4 : 0;
    const int hi_c = (w4 <= WW - 8) ? w4 + 4 : WW - 8;

    // Per-pixel column validity (pixel p is col w4+p).
    bool cvlo[4], cvhi[4];
    #pragma unroll
    for (int p = 0; p < 4; ++p) {
        cvlo[p] = (w4 + p >= 2);
        cvhi[p] = (w4 + p <= WW - 3);
    }

    // ---- Pass 1: partial scores over this d-half ----
    float s[4][9];
    #pragma unroll
    for (int p = 0; p < 4; ++p)
        #pragma unroll
        for (int n = 0; n < 9; ++n) s[p][n] = 0.f;

    const float* qp = q + dbase + rowbase;
    const float* kp = k + dbase + rowbase;

    for (int c = 0; c < HALF; c += CHUNK) {
        float4 qreg[CHUNK];
        float4 kk[CHUNK][3][3];   // [u][tap-row][lo/ce/hi]
        #pragma unroll
        for (int u = 0; u < CHUNK; ++u) {
            const float* kc = kp + (size_t)(c + u) * PLANE;
            qreg[u] = *(const float4*)(qp + (size_t)(c + u) * PLANE + w4);
            #pragma unroll
            for (int ti = 0; ti < 3; ++ti) {
                const float* kr = kc + roff[ti];
                kk[u][ti][0] = *(const float4*)(kr + lo_c);
                kk[u][ti][1] = *(const float4*)(kr + w4);
                kk[u][ti][2] = *(const float4*)(kr + hi_c);
            }
        }
        #pragma unroll
        for (int u = 0; u < CHUNK; ++u) {
            const float qa[4] = { qreg[u].x, qreg[u].y, qreg[u].z, qreg[u].w };
            #pragma unroll
            for (int ti = 0; ti < 3; ++ti) {
                const float c12[12] = {
                    kk[u][ti][0].x, kk[u][ti][0].y, kk[u][ti][0].z, kk[u][ti][0].w,
                    kk[u][ti][1].x, kk[u][ti][1].y, kk[u][ti][1].z, kk[u][ti][1].w,
                    kk[u][ti][2].x, kk[u][ti][2].y, kk[u][ti][2].z, kk[u][ti][2].w };
                #pragma unroll
                for (int p = 0; p < 4; ++p) {
                    s[p][ti * 3 + 0] = fmaf(qa[p], c12[2 + p], s[p][ti * 3 + 0]);
                    s[p][ti * 3 + 1] = fmaf(qa[p], c12[4 + p], s[p][ti * 3 + 1]);
                    s[p][ti * 3 + 2] = fmaf(qa[p], c12[6 + p], s[p][ti * 3 + 2]);
                }
            }
        }
    }

    // ---- Reduce the two d-halves (lane bit 5) ----
    #pragma unroll
    for (int p = 0; p < 4; ++p)
        #pragma unroll
        for (int n = 0; n < 9; ++n)
            s[p][n] += __shfl_xor(s[p][n], 32);

    // Cancel garbage (invalid taps: score exactly 0, still in denominator).
    #pragma unroll
    for (int p = 0; p < 4; ++p) {
        const bool rv[3] = { hlo, true, hhi };
        #pragma unroll
        for (int ti = 0; ti < 3; ++ti) {
            if (!(rv[ti] && cvlo[p])) s[p][ti * 3 + 0] = 0.f;
            if (!rv[ti])              s[p][ti * 3 + 1] = 0.f;
            if (!(rv[ti] && cvhi[p])) s[p][ti * 3 + 2] = 0.f;
        }
    }

    // ---- Softmax over 9 taps, per pixel ----
    const float scale = 0.17677669529663687f;  // 32^-0.5
    #pragma unroll
    for (int p = 0; p < 4; ++p) {
        float m = -3.4e38f;
        #pragma unroll
        for (int n = 0; n < 9; ++n) { s[p][n] *= scale; m = fmaxf(m, s[p][n]); }
        float sum = 0.f;
        #pragma unroll
        for (int n = 0; n < 9; ++n) { s[p][n] = __expf(s[p][n] - m); sum += s[p][n]; }
        const float inv = 1.f / sum;
        #pragma unroll
        for (int n = 0; n < 9; ++n) s[p][n] *= inv;
    }

    // Zero weights of invalid taps (reference v is zero-padded there).
    #pragma unroll
    for (int p = 0; p < 4; ++p) {
        const bool rv[3] = { hlo, true, hhi };
        #pragma unroll
        for (int ti = 0; ti < 3; ++ti) {
            if (!(rv[ti] && cvlo[p])) s[p][ti * 3 + 0] = 0.f;
            if (!rv[ti])              s[p][ti * 3 + 1] = 0.f;
            if (!(rv[ti] && cvhi[p])) s[p][ti * 3 + 2] = 0.f;
        }
    }

    // ---- Pass 2: PV for this d-half ----
    const float* vp = v + dbase + rowbase;
    float*       op = out + dbase + rowbase;

    for (int c = 0; c < HALF; c += CHUNK) {
        float4 vv[CHUNK][3][3];
        #pragma unroll
        for (int u = 0; u < CHUNK; ++u) {
            const float* vc = vp + (size_t)(c + u) * PLANE;
            #pragma unroll
            for (int ti = 0; ti < 3; ++ti) {
                const float* vr = vc + roff[ti];
                vv[u][ti][0] = *(const float4*)(vr + lo_c);
                vv[u][ti][1] = *(const float4*)(vr + w4);
                vv[u][ti][2] = *(const float4*)(vr + hi_c);
            }
        }
        #pragma unroll
        for (int u = 0; u < CHUNK; ++u) {
            float a[4] = { 0.f, 0.f, 0.f, 0.f };
            #pragma unroll
            for (int ti = 0; ti < 3; ++ti) {
                const float c12[12] = {
                    vv[u][ti][0].x, vv[u][ti][0].y, vv[u][ti][0].z, vv[u][ti][0].w,
                    vv[u][ti][1].x, vv[u][ti][1].y, vv[u][ti][1].z, vv[u][ti][1].w,
                    vv[u][ti][2].x, vv[u][ti][2].y, vv[u][ti][2].z, vv[u][ti][2].w };
                #pragma unroll
                for (int p = 0; p < 4; ++p) {
                    a[p] = fmaf(s[p][ti * 3 + 0], c12[2 + p], a[p]);
                    a[p] = fmaf(s[p][ti * 3 + 1], c12[4 + p], a[p]);
                    a[p] = fmaf(s[p][ti * 3 + 2], c12[6 + p], a[p]);
                }
            }
            *(float4*)(op + (size_t)(c + u) * PLANE + w4) =
                make_float4(a[0], a[1], a[2], a[3]);
        }
    }
}

extern "C" void kernel_launch(void* const* d_in, const int* in_sizes, int n_in,
                              void* d_out, int out_size, void* d_ws, size_t ws_size,
                              hipStream_t stream) {
    const float* q = (const float*)d_in[0];
    const float* k = (const float*)d_in[1];
    const float* v = (const float*)d_in[2];
    float* out = (float*)d_out;

    dim3 grid(BB * HH / 4);  // 512 blocks; block = 4 consecutive (b,h) rows
    dim3 block(256);         // 4 waves; wave = one full row x 2 d-halves
    dilate_attn_kernel<<<grid, block, 0, stream>>>(q, k, v, out);
}

// Round 8
// 35.638 us; speedup vs baseline: 1.3622x; 1.1237x over previous
//
#include <hip/hip_runtime.h>

// DilateAttention: q,k,v [B=16, d=32, H=128, W=128] fp32, kernel=3, dilation=2, pad=2.
// Per-pixel 1x9 attention over dilated 3x3 window; OOB taps are zero-padded
// (score 0, value 0) and participate in the softmax denominator.
//
// R8: minimize per-CU L1 cache-line lookups (the R7 post-mortem model: lookups
// ~1/cy/CU bind all prior rounds; instr count does not).
//  Pass 1 (shifted-q): lane w loads k[row][w] (3) + q[w-2],q[w],q[w+2] (3) per d
//    and accumulates cross-products P_lo[w]=sum q[w+2]k[w] (the lo-score of
//    pixel w+2), P_ce, P_hi[w]=sum q[w-2]k[w]. Scores recovered AFTER the
//    d-loop by 6 bpermutes + 24-float LDS seam exchange (1 barrier total).
//    6 VMEM/d (~30 lines) vs R4's 10 (~50 lines).
//  Pass 2: load v_ce (3) + 2-line seam load (3) per d; v[w+-2] via bpermute.
//    6 VMEM/d (~21 lines) vs 9 (~45), work shifted onto the idle LDS pipe.
// No d-split (R6/R7 lesson: 2-plane instrs double line lookups).
// Kept from R4: clamped unpredicated loads + tv[] cancellation, CHUNK=4
// phase-split batches, XCD-chunk swizzle, 2048x128 launch.

#define BB 16
#define HD 32
#define HH 128
#define WW 128
#define PLANE (HH * WW)
#define CHUNK 4

__global__ __launch_bounds__(128) void dilate_attn_kernel(
    const float* __restrict__ q,
    const float* __restrict__ k,
    const float* __restrict__ v,
    float* __restrict__ out)
{
    __shared__ float ex_lo[2][3][2];   // [wave][tap-row][lane62/63] P_lo
    __shared__ float ex_hi[2][3][2];   // [wave][tap-row][lane0/1]  P_hi

    const int tid  = threadIdx.x;      // 0..127 == column w
    const int wave = tid >> 6;         // 0/1
    const int lane = tid & 63;
    const int w0   = wave << 6;
    const int w    = tid;

    const int bid   = blockIdx.x;                    // 0..2047
    const int rowid = (bid & 7) * 256 + (bid >> 3);  // XCD-chunk swizzle
    const int h = rowid & (HH - 1);
    const int b = rowid >> 7;

    const size_t base = (size_t)b * HD * PLANE + (size_t)h * WW;

    const bool hlo = (h >= 2), hhi = (h <= HH - 3);
    const int  roff[3] = { hlo ? -2 * WW : 0, 0, hhi ? 2 * WW : 0 };
    const bool wlo = (w >= 2), whi = (w <= WW - 3);
    const bool tv[9] = { hlo && wlo, hlo, hlo && whi,
                         wlo,        true, whi,
                         hhi && wlo, hhi, hhi && whi };

    // Shifted-q column addresses (clamped; clamp cases feed cancelled taps).
    const int cqm2 = wlo ? w - 2 : 0;
    const int cqp2 = whi ? w + 2 : WW - 1;

    // Pass-2 seam column: lanes 0,1 -> w0-2,w0-1; lanes 62,63 -> w0+64,w0+65;
    // others load w0 (1-line, value unused). Clamped at image edges (cancelled).
    int scol = w0;
    if (lane < 2)        scol = w0 + lane - 2;
    else if (lane >= 62) scol = w0 + lane + 2;
    scol = scol < 0 ? 0 : (scol > WW - 1 ? WW - 1 : scol);

    const int idxm2 = (lane >= 2) ? lane - 2 : 0;
    const int idxp2 = (lane < 62) ? lane + 2 : 63;

    // ---- Pass 1: cross-product accumulation (6 loads/d, no in-loop shuffles) ----
    float Plo[3] = {0.f, 0.f, 0.f};
    float Pce[3] = {0.f, 0.f, 0.f};
    float Phi[3] = {0.f, 0.f, 0.f};

    const float* qrow = q + base;
    const float* krow = k + base;

    for (int c = 0; c < HD; c += CHUNK) {
        float kr[CHUNK][3], q0[CHUNK], qm[CHUNK], qp[CHUNK];
        #pragma unroll
        for (int u = 0; u < CHUNK; ++u) {
            const size_t dp = (size_t)(c + u) * PLANE;
            kr[u][0] = krow[dp + roff[0] + w];
            kr[u][1] = krow[dp + w];
            kr[u][2] = krow[dp + roff[2] + w];
            q0[u]    = qrow[dp + w];
            qm[u]    = qrow[dp + cqm2];
            qp[u]    = qrow[dp + cqp2];
        }
        #pragma unroll
        for (int u = 0; u < CHUNK; ++u) {
            #pragma unroll
            for (int r = 0; r < 3; ++r) {
                Plo[r] = fmaf(qp[u], kr[u][r], Plo[r]);  // -> pixel w+2's lo
                Pce[r] = fmaf(q0[u], kr[u][r], Pce[r]);  // -> pixel w's ce
                Phi[r] = fmaf(qm[u], kr[u][r], Phi[r]);  // -> pixel w-2's hi
            }
        }
    }

    // Seam exchange between the block's two waves (cols 62/63 <-> 64/65).
    if (lane < 2) {
        #pragma unroll
        for (int r = 0; r < 3; ++r) ex_hi[wave][r][lane] = Phi[r];
    }
    if (lane >= 62) {
        #pragma unroll
        for (int r = 0; r < 3; ++r) ex_lo[wave][r][lane - 62] = Plo[r];
    }
    __syncthreads();

    // Recover scores: s_lo[w] = P_lo[w-2], s_hi[w] = P_hi[w+2].
    float s[9];
    #pragma unroll
    for (int r = 0; r < 3; ++r) {
        float slo = __shfl(Plo[r], idxm2);
        if (lane < 2)  slo = ex_lo[wave ^ 1][r][lane];
        float shi = __shfl(Phi[r], idxp2);
        if (lane >= 62) shi = ex_hi[wave ^ 1][r][lane - 62];
        s[r * 3 + 0] = slo;
        s[r * 3 + 1] = Pce[r];
        s[r * 3 + 2] = shi;
    }

    // Cancel garbage (invalid taps: score exactly 0, still in denominator).
    #pragma unroll
    for (int n = 0; n < 9; ++n) if (!tv[n]) s[n] = 0.f;

    // ---- Softmax over 9 taps ----
    const float scale = 0.17677669529663687f;  // 32^-0.5
    float m = -3.4e38f;
    #pragma unroll
    for (int n = 0; n < 9; ++n) { s[n] *= scale; m = fmaxf(m, s[n]); }
    float sum = 0.f;
    #pragma unroll
    for (int n = 0; n < 9; ++n) { s[n] = __expf(s[n] - m); sum += s[n]; }
    const float inv = 1.f / sum;
    #pragma unroll
    for (int n = 0; n < 9; ++n) s[n] *= inv;

    // Zero weights of invalid taps (reference v is zero-padded there).
    #pragma unroll
    for (int n = 0; n < 9; ++n) if (!tv[n]) s[n] = 0.f;

    // ---- Pass 2: PV with ce+seam loads, v[w+-2] via bpermute ----
    const float* vrow = v + base;
    float*       orow = out + base;

    for (int c = 0; c < HD; c += CHUNK) {
        float vce[CHUNK][3], vsm[CHUNK][3];
        #pragma unroll
        for (int u = 0; u < CHUNK; ++u) {
            const size_t dp = (size_t)(c + u) * PLANE;
            #pragma unroll
            for (int r = 0; r < 3; ++r) {
                vce[u][r] = vrow[dp + roff[r] + w];
                vsm[u][r] = vrow[dp + roff[r] + scol];
            }
        }
        #pragma unroll
        for (int u = 0; u < CHUNK; ++u) {
            float acc = 0.f;
            #pragma unroll
            for (int r = 0; r < 3; ++r) {
                float vlo = __shfl(vce[u][r], idxm2);
                vlo = (lane < 2) ? vsm[u][r] : vlo;
                float vhi = __shfl(vce[u][r], idxp2);
                vhi = (lane >= 62) ? vsm[u][r] : vhi;
                acc = fmaf(s[r * 3 + 0], vlo,       acc);
                acc = fmaf(s[r * 3 + 1], vce[u][r], acc);
                acc = fmaf(s[r * 3 + 2], vhi,       acc);
            }
            orow[(size_t)(c + u) * PLANE + w] = acc;
        }
    }
}

extern "C" void kernel_launch(void* const* d_in, const int* in_sizes, int n_in,
                              void* d_out, int out_size, void* d_ws, size_t ws_size,
                              hipStream_t stream) {
    const float* q = (const float*)d_in[0];
    const float* k = (const float*)d_in[1];
    const float* v = (const float*)d_in[2];
    float* out = (float*)d_out;

    dim3 grid(BB * HH);   // 2048 blocks, one (b,h) row each
    dim3 block(WW);       // 128 threads = 2 waves
    dilate_attn_kernel<<<grid, block, 0, stream>>>(q, k, v, out);
}

// Round 9
// 34.714 us; speedup vs baseline: 1.3985x; 1.0266x over previous
//
#include <hip/hip_runtime.h>

// DilateAttention: q,k,v [B=16, d=32, H=128, W=128] fp32, kernel=3, dilation=2, pad=2.
// Per-pixel 1x9 attention over dilated 3x3 window; OOB taps are zero-padded
// (score 0, value 0) and participate in the softmax denominator.
//
// R9: float2 lanes + cross-product trick on BOTH passes.
//  - wave = one full 128-px row (lane w owns px 2w,2w+1). All loads are
//    single-segment 512B float2; all shuffle seams are image edges ->
//    wrap garbage lands only on tv-cancelled taps. No LDS, no barrier.
//  - pass 1 (shifted q): per d load k_ce x3 rows + q_lo/ce/hi (6 instrs);
//    accumulate P_lo = q_hi*k, P_ce = q_ce*k, P_hi = q_lo*k; recover the
//    9 scores after the d-loop with 12 shuffles total.
//  - pass 2 (shifted weights): pre-shift+pre-zero the softmax weights once
//    (12 shuffles); per d load v_ce x3 rows, form t_lo/t_ce/t_hi, recombine
//    with 4 shuffles, store. 4 VMEM/d vs 10.
// Kept: clamped unpredicated loads + validity cancellation, CHUNK=4
// phase-split batches, XCD-chunk swizzle.

#define BB 16
#define HD 32
#define HH 128
#define WW 128
#define PLANE (HH * WW)
#define CHUNK 4

__global__ __launch_bounds__(256) void dilate_attn_kernel(
    const float* __restrict__ q,
    const float* __restrict__ k,
    const float* __restrict__ v,
    float* __restrict__ out)
{
    const int tid  = threadIdx.x;
    const int wv   = tid >> 6;         // wave 0..3 = row within block
    const int lane = tid & 63;
    const int w2   = lane * 2;         // px pair (w2, w2+1)

    const int bid   = blockIdx.x;                   // 0..511
    const int tile  = (bid & 7) * 64 + (bid >> 3);  // XCD-chunk swizzle
    const int rowid = tile * 4 + wv;                // 0..2047
    const int h = rowid & (HH - 1);
    const int b = rowid >> 7;

    const size_t base = (size_t)b * HD * PLANE + (size_t)h * WW;

    // Row validity (wave-uniform) and clamped row offsets.
    const bool hlo = (h >= 2), hhi = (h <= HH - 3);
    const int  roff[3] = { hlo ? -2 * WW : 0, 0, hhi ? 2 * WW : 0 };
    const bool rv[3]   = { hlo, true, hhi };

    // Column validity: px0=2w needs col 2w-2 (lo) -> lane>=1; col 2w+2 (hi)
    // -> lane<=62. Same for px1=2w+1 (cols 2w-1 / 2w+3). Lane-uniform pair.
    const bool tvlo = (lane >= 1), tvhi = (lane <= 62);

    // Clamped shifted-q columns (even -> float2-aligned; garbage cancelled).
    const int cql = tvlo ? w2 - 2 : 0;    // q_lo
    const int cqh = tvhi ? w2 + 2 : w2;   // q_hi

    const int im1 = (lane + 63) & 63;
    const int ip1 = (lane + 1) & 63;

    // ---- Pass 1: cross-products over d (6 float2 loads/d) ----
    float Plo0[3] = {0,0,0}, Plo1[3] = {0,0,0};   // -> s_lo of px+2 (lane+1)
    float Pce0[3] = {0,0,0}, Pce1[3] = {0,0,0};   // -> s_ce of px   (lane)
    float Phi0[3] = {0,0,0}, Phi1[3] = {0,0,0};   // -> s_hi of px-2 (lane-1)

    const float* qrow = q + base;
    const float* krow = k + base;

    for (int c = 0; c < HD; c += CHUNK) {
        float2 ql[CHUNK], qc[CHUNK], qh[CHUNK], kr[CHUNK][3];
        #pragma unroll
        for (int u = 0; u < CHUNK; ++u) {
            const size_t dp = (size_t)(c + u) * PLANE;
            ql[u] = *(const float2*)(qrow + dp + cql);
            qc[u] = *(const float2*)(qrow + dp + w2);
            qh[u] = *(const float2*)(qrow + dp + cqh);
            #pragma unroll
            for (int r = 0; r < 3; ++r)
                kr[u][r] = *(const float2*)(krow + dp + roff[r] + w2);
        }
        #pragma unroll
        for (int u = 0; u < CHUNK; ++u) {
            #pragma unroll
            for (int r = 0; r < 3; ++r) {
                Plo0[r] = fmaf(qh[u].x, kr[u][r].x, Plo0[r]);
                Plo1[r] = fmaf(qh[u].y, kr[u][r].y, Plo1[r]);
                Pce0[r] = fmaf(qc[u].x, kr[u][r].x, Pce0[r]);
                Pce1[r] = fmaf(qc[u].y, kr[u][r].y, Pce1[r]);
                Phi0[r] = fmaf(ql[u].x, kr[u][r].x, Phi0[r]);
                Phi1[r] = fmaf(ql[u].y, kr[u][r].y, Phi1[r]);
            }
        }
    }

    // ---- Recover scores (12 shuffles): s_lo[px]=P_lo[lane-1], s_hi[px]=P_hi[lane+1] ----
    float s0[9], s1[9];
    #pragma unroll
    for (int r = 0; r < 3; ++r) {
        const float a0 = __shfl(Plo0[r], im1), a1 = __shfl(Plo1[r], im1);
        const float b0 = __shfl(Phi0[r], ip1), b1 = __shfl(Phi1[r], ip1);
        const bool vlo = rv[r] && tvlo, vhi = rv[r] && tvhi;
        s0[r * 3 + 0] = vlo ? a0 : 0.f;      s1[r * 3 + 0] = vlo ? a1 : 0.f;
        s0[r * 3 + 1] = rv[r] ? Pce0[r] : 0.f; s1[r * 3 + 1] = rv[r] ? Pce1[r] : 0.f;
        s0[r * 3 + 2] = vhi ? b0 : 0.f;      s1[r * 3 + 2] = vhi ? b1 : 0.f;
    }

    // ---- Softmax over 9 taps per pixel (invalid taps enter as score 0) ----
    const float scale = 0.17677669529663687f;  // 32^-0.5
    {
        float m0 = -3.4e38f, m1 = -3.4e38f;
        #pragma unroll
        for (int n = 0; n < 9; ++n) {
            s0[n] *= scale; m0 = fmaxf(m0, s0[n]);
            s1[n] *= scale; m1 = fmaxf(m1, s1[n]);
        }
        float sum0 = 0.f, sum1 = 0.f;
        #pragma unroll
        for (int n = 0; n < 9; ++n) {
            s0[n] = __expf(s0[n] - m0); sum0 += s0[n];
            s1[n] = __expf(s1[n] - m1); sum1 += s1[n];
        }
        const float i0 = 1.f / sum0, i1 = 1.f / sum1;
        #pragma unroll
        for (int n = 0; n < 9; ++n) { s0[n] *= i0; s1[n] *= i1; }
    }

    // Zero weights of invalid taps (reference v is zero-padded there).
    #pragma unroll
    for (int r = 0; r < 3; ++r) {
        const bool vlo = rv[r] && tvlo, vhi = rv[r] && tvhi;
        if (!vlo)   { s0[r * 3 + 0] = 0.f; s1[r * 3 + 0] = 0.f; }
        if (!rv[r]) { s0[r * 3 + 1] = 0.f; s1[r * 3 + 1] = 0.f; }
        if (!vhi)   { s0[r * 3 + 2] = 0.f; s1[r * 3 + 2] = 0.f; }
    }

    // ---- Pre-shift weights for pass 2 (12 shuffles, zeroed at wrap) ----
    // w_lo@lane u = s_lo@(u+1) (weight of out px 2u+2 applied to v@u);
    // w_hi@lane u = s_hi@(u-1).
    float wl0[3], wl1[3], wh0[3], wh1[3], wc0[3], wc1[3];
    #pragma unroll
    for (int r = 0; r < 3; ++r) {
        const float a0 = __shfl(s0[r * 3 + 0], ip1), a1 = __shfl(s1[r * 3 + 0], ip1);
        const float b0 = __shfl(s0[r * 3 + 2], im1), b1 = __shfl(s1[r * 3 + 2], im1);
        wl0[r] = tvhi ? a0 : 0.f;  wl1[r] = tvhi ? a1 : 0.f;  // lane 63 -> 0
        wh0[r] = tvlo ? b0 : 0.f;  wh1[r] = tvlo ? b1 : 0.f;  // lane 0  -> 0
        wc0[r] = s0[r * 3 + 1];    wc1[r] = s1[r * 3 + 1];
    }

    // ---- Pass 2: PV with 3 v loads + 1 store + 4 shuffles per d ----
    const float* vrow = v + base;
    float*       orow = out + base;

    for (int c = 0; c < HD; c += CHUNK) {
        float2 vr[CHUNK][3];
        #pragma unroll
        for (int u = 0; u < CHUNK; ++u) {
            const size_t dp = (size_t)(c + u) * PLANE;
            #pragma unroll
            for (int r = 0; r < 3; ++r)
                vr[u][r] = *(const float2*)(vrow + dp + roff[r] + w2);
        }
        #pragma unroll
        for (int u = 0; u < CHUNK; ++u) {
            float tl0 = 0.f, tl1 = 0.f, tc0 = 0.f, tc1 = 0.f, th0 = 0.f, th1 = 0.f;
            #pragma unroll
            for (int r = 0; r < 3; ++r) {
                tl0 = fmaf(wl0[r], vr[u][r].x, tl0);
                tl1 = fmaf(wl1[r], vr[u][r].y, tl1);
                tc0 = fmaf(wc0[r], vr[u][r].x, tc0);
                tc1 = fmaf(wc1[r], vr[u][r].y, tc1);
                th0 = fmaf(wh0[r], vr[u][r].x, th0);
                th1 = fmaf(wh1[r], vr[u][r].y, th1);
            }
            // out[px] = t_ce + t_lo(from lane-1) + t_hi(from lane+1)
            const float rl0 = __shfl(tl0, im1), rl1 = __shfl(tl1, im1);
            const float rh0 = __shfl(th0, ip1), rh1 = __shfl(th1, ip1);
            *(float2*)(orow + (size_t)(c + u) * PLANE + w2) =
                make_float2(tc0 + rl0 + rh0, tc1 + rl1 + rh1);
        }
    }
}

extern "C" void kernel_launch(void* const* d_in, const int* in_sizes, int n_in,
                              void* d_out, int out_size, void* d_ws, size_t ws_size,
                              hipStream_t stream) {
    const float* q = (const float*)d_in[0];
    const float* k = (const float*)d_in[1];
    const float* v = (const float*)d_in[2];
    float* out = (float*)d_out;

    dim3 grid(BB * HH / 4);  // 512 blocks = 4 rows each
    dim3 block(256);         // 4 waves; wave = one full row
    dilate_attn_kernel<<<grid, block, 0, stream>>>(q, k, v, out);
}